// Round 1
// baseline (232.729 us; speedup 1.0000x reference)
//
#include <hip/hip_runtime.h>

#define NKEYS 64

// out[i] = t[x[i]] where t is a 64-entry table derived from (keys, b):
//   t[v] = b[k] if keys[k] == (float)v for integral v in [0,64), else 0.
//
// v2: register-resident table (one entry per lane) + ds_bpermute lookups,
//     grid-stride with ~2048 blocks (8 blocks/CU = full occupancy at 256 thr),
//     non-temporal stores for the write-once output.
__global__ __launch_bounds__(256) void sel_xform_kernel(
    const int4* __restrict__ in,
    const float* __restrict__ b,
    const float* __restrict__ keys,
    float4* __restrict__ out,
    int nvec, int ntail, const int* __restrict__ in_tail, float* __restrict__ out_tail)
{
    __shared__ float t[NKEYS];
    const int tid = threadIdx.x;
    if (tid < NKEYS) t[tid] = 0.0f;
    __syncthreads();
    if (tid < NKEYS) {
        const float kv = keys[tid];
        const int iv = (int)kv;
        if ((float)iv == kv && iv >= 0 && iv < NKEYS) {
            t[iv] = b[tid];   // keys are unique -> no write race
        }
    }
    __syncthreads();

    // Lane l of every wave holds t[l] in a register. This read is 2-way bank
    // aliased (free); hot-loop lookups become conflict-free ds_bpermute.
    const float tv = t[tid & 63];

    const int stride = gridDim.x * blockDim.x;
    // Loop condition is block-uniform so every lane of a wave reaches the
    // shuffles together (bpermute sources must be active lanes).
    for (int base = blockIdx.x * blockDim.x; base < nvec; base += stride) {
        const int i = base + tid;
        int4 v;
        if (i < nvec) {
            v = in[i];
        } else {
            v = make_int4(0, 0, 0, 0);
        }
        const float sx = __shfl(tv, v.x & 63);
        const float sy = __shfl(tv, v.y & 63);
        const float sz = __shfl(tv, v.z & 63);
        const float sw = __shfl(tv, v.w & 63);
        if (i < nvec) {
            float4 o;
            o.x = ((unsigned)v.x < NKEYS) ? sx : 0.0f;
            o.y = ((unsigned)v.y < NKEYS) ? sy : 0.0f;
            o.z = ((unsigned)v.z < NKEYS) ? sz : 0.0f;
            o.w = ((unsigned)v.w < NKEYS) ? sw : 0.0f;
            // Output is write-once, never re-read: keep it out of L2/L3 so the
            // Infinity Cache stays available for the input stream.
            typedef float __attribute__((ext_vector_type(4))) f32x4;
            __builtin_nontemporal_store(*reinterpret_cast<const f32x4*>(&o),
                                        reinterpret_cast<f32x4*>(&out[i]));
        }
    }

    // Scalar tail (n % 4 elements), handled by the first few threads of block 0.
    if (blockIdx.x == 0 && tid < ntail) {
        const int v = in_tail[tid];
        out_tail[tid] = ((unsigned)v < NKEYS) ? t[v] : 0.0f;
    }
}

extern "C" void kernel_launch(void* const* d_in, const int* in_sizes, int n_in,
                              void* d_out, int out_size, void* d_ws, size_t ws_size,
                              hipStream_t stream) {
    const int*   x    = (const int*)d_in[0];     // inputs, int32, [8,4096,1024]
    const float* b    = (const float*)d_in[1];   // per-key bias, [64]
    const float* keys = (const float*)d_in[2];   // sorted unique keys, [64]
    float* out = (float*)d_out;

    const int n    = in_sizes[0];
    const int nvec = n >> 2;        // int4 / float4 groups
    const int ntail = n & 3;

    const int block = 256;
    // 2048 blocks = 8 blocks/CU x 256 CUs = 32 waves/CU (full occupancy at
    // this register count); grid-stride amortizes table setup over ~16 iters.
    int grid = (nvec + block - 1) / block;
    if (grid > 2048) grid = 2048;
    if (grid < 1) grid = 1;

    sel_xform_kernel<<<grid, block, 0, stream>>>(
        (const int4*)x, b, keys, (float4*)out,
        nvec, ntail, x + (nvec << 2), out + (nvec << 2));
}